// Round 2
// baseline (515.245 us; speedup 1.0000x reference)
//
#include <hip/hip_runtime.h>
#include <math.h>

#define N_NODES 50000
#define N_EDGES 800000
#define D_FEAT 128

__device__ __forceinline__ unsigned int float_to_ord(float f) {
    unsigned int u = __float_as_uint(f);
    return (u & 0x80000000u) ? ~u : (u | 0x80000000u);
}
__device__ __forceinline__ float ord_to_float(unsigned int u) {
    u = (u & 0x80000000u) ? (u ^ 0x80000000u) : ~u;
    return __uint_as_float(u);
}

// Global max over x (ordered-uint atomicMax, one per block)
__global__ void k_max(const float* __restrict__ x, unsigned int* __restrict__ maxbits, int total) {
    float m = -INFINITY;
    for (int i = blockIdx.x * blockDim.x + threadIdx.x; i < total; i += gridDim.x * blockDim.x)
        m = fmaxf(m, x[i]);
    for (int off = 32; off > 0; off >>= 1)
        m = fmaxf(m, __shfl_down(m, off, 64));
    __shared__ float smem[16];
    int lane = threadIdx.x & 63, wid = threadIdx.x >> 6;
    if (lane == 0) smem[wid] = m;
    __syncthreads();
    if (threadIdx.x == 0) {
        int nw = blockDim.x >> 6;
        for (int i = 1; i < nw; ++i) m = fmaxf(m, smem[i]);
        atomicMax(maxbits, float_to_ord(m));
    }
}

// Degrees: deg_row (bucketing over row), deg_col (norm over col)
__global__ void k_count(const int* __restrict__ row, const int* __restrict__ col,
                        int* __restrict__ deg_row, int* __restrict__ deg_col) {
    int e = blockIdx.x * blockDim.x + threadIdx.x;
    if (e < N_EDGES) {
        atomicAdd(&deg_row[row[e]], 1);
        atomicAdd(&deg_col[col[e]], 1);
    }
}

// Single-block chunked exclusive scan of deg_row -> row_ptr/cursor; dis from deg_col
__global__ void __launch_bounds__(1024) k_scan(const int* __restrict__ deg_row,
                                               const int* __restrict__ deg_col,
                                               int* __restrict__ row_ptr,
                                               int* __restrict__ cursor,
                                               float* __restrict__ dis) {
    __shared__ int partial[1024];
    const int CHUNK = (N_NODES + 1023) / 1024;  // 49
    int t = threadIdx.x;
    int beg = t * CHUNK;
    int end = min(beg + CHUNK, N_NODES);
    int s = 0;
    for (int i = beg; i < end; ++i) s += deg_row[i];
    partial[t] = s;
    __syncthreads();
    for (int off = 1; off < 1024; off <<= 1) {
        int v = (t >= off) ? partial[t - off] : 0;
        __syncthreads();
        partial[t] += v;
        __syncthreads();
    }
    int run = partial[t] - s;  // exclusive prefix of this chunk
    for (int i = beg; i < end; ++i) {
        int dv = deg_row[i];
        row_ptr[i] = run;
        cursor[i] = run;
        int dc = deg_col[i];
        dis[i] = (dc > 0) ? rsqrtf((float)dc) : 0.0f;
        run += dv;
    }
    if (t == 1023) row_ptr[N_NODES] = run;  // == E
}

// Bucket edges by row into CSR order (in-row order arbitrary; fp sums tolerant)
__global__ void k_scatter(const int* __restrict__ row, const int* __restrict__ col,
                          int* __restrict__ cursor, int* __restrict__ col_sorted) {
    int e = blockIdx.x * blockDim.x + threadIdx.x;
    if (e < N_EDGES) {
        int r = row[e];
        int pos = atomicAdd(&cursor[r], 1);
        col_sorted[pos] = col[e];
    }
}

// One 128-thread block per node; thread d owns feature d.
// S = sum norm*sm, T = sum norm*sm*x ; out = T/(S+1e-6) + (1+eps)*x
__global__ void __launch_bounds__(128) k_agg(const float* __restrict__ x,
                                             const float* __restrict__ dis,
                                             const int* __restrict__ row_ptr,
                                             const int* __restrict__ col_sorted,
                                             const unsigned int* __restrict__ maxbits,
                                             const float* __restrict__ eps_p,
                                             const float* __restrict__ p_p,
                                             float* __restrict__ out) {
    int n = blockIdx.x;
    int d = threadIdx.x;
    float pp = 2.0f / (1.0f + __expf(-p_p[0]));
    float M  = pp * ord_to_float(maxbits[0]);
    float dn = dis[n];
    int beg = row_ptr[n], end = row_ptr[n + 1];
    float S = 0.0f, T = 0.0f;
    for (int i = beg; i < end; ++i) {
        int c = col_sorted[i];
        float nrm = dn * dis[c];
        float xv = x[c * D_FEAT + d];
        float sm = __expf(fmaf(pp, xv, -M));
        float w = nrm * sm;
        S += w;
        T = fmaf(w, xv, T);
    }
    float xn = x[n * D_FEAT + d];
    out[n * D_FEAT + d] = T / (S + 1e-6f) + (1.0f + eps_p[0]) * xn;
}

extern "C" void kernel_launch(void* const* d_in, const int* in_sizes, int n_in,
                              void* d_out, int out_size, void* d_ws, size_t ws_size,
                              hipStream_t stream) {
    const float* x   = (const float*)d_in[0];
    const int*   ei  = (const int*)d_in[1];   // [2, E]: row = ei[0:E], col = ei[E:2E]
    const float* eps = (const float*)d_in[2];
    const float* p   = (const float*)d_in[3];
    float* out = (float*)d_out;

    const int* row = ei;
    const int* col = ei + N_EDGES;

    // Workspace layout (4B elements)
    char* ws = (char*)d_ws;
    int*   deg_row    = (int*)ws;                                   // N
    int*   deg_col    = (int*)(ws + 4 * N_NODES);                   // N
    unsigned int* maxbits = (unsigned int*)(ws + 4 * 2 * N_NODES);  // 1
    int*   row_ptr    = (int*)(ws + 4 * (2 * N_NODES + 1));         // N+1
    int*   cursor     = (int*)(ws + 4 * (3 * N_NODES + 2));         // N
    float* dis        = (float*)(ws + 4 * (4 * N_NODES + 2));       // N
    int*   col_sorted = (int*)(ws + 4 * (5 * N_NODES + 2));         // E
    // total: 4*(5N+2) + 4E ≈ 4.2 MB

    // zero deg_row + deg_col + maxbits in one shot
    hipMemsetAsync(ws, 0, 4 * (2 * N_NODES + 1), stream);

    k_max<<<2048, 256, 0, stream>>>(x, maxbits, N_NODES * D_FEAT);
    k_count<<<(N_EDGES + 255) / 256, 256, 0, stream>>>(row, col, deg_row, deg_col);
    k_scan<<<1, 1024, 0, stream>>>(deg_row, deg_col, row_ptr, cursor, dis);
    k_scatter<<<(N_EDGES + 255) / 256, 256, 0, stream>>>(row, col, cursor, col_sorted);
    k_agg<<<N_NODES, D_FEAT, 0, stream>>>(x, dis, row_ptr, col_sorted, maxbits, eps, p, out);
}

// Round 3
// 287.416 us; speedup vs baseline: 1.7927x; 1.7927x over previous
//
#include <hip/hip_runtime.h>
#include <math.h>

#define N_NODES 50000
#define N_EDGES 800000
#define D_FEAT 128
#define SCAN_B 256
#define N_SCAN_BLOCKS ((N_NODES + SCAN_B - 1) / SCAN_B)  // 196

__device__ __forceinline__ unsigned int float_to_ord(float f) {
    unsigned int u = __float_as_uint(f);
    return (u & 0x80000000u) ? ~u : (u | 0x80000000u);
}
__device__ __forceinline__ float ord_to_float(unsigned int u) {
    u = (u & 0x80000000u) ? (u ^ 0x80000000u) : ~u;
    return __uint_as_float(u);
}

// Global max over x (ordered-uint atomicMax, one per block)
__global__ void k_max(const float* __restrict__ x, unsigned int* __restrict__ maxbits, int total) {
    float m = -INFINITY;
    for (int i = blockIdx.x * blockDim.x + threadIdx.x; i < total; i += gridDim.x * blockDim.x)
        m = fmaxf(m, x[i]);
    for (int off = 32; off > 0; off >>= 1)
        m = fmaxf(m, __shfl_down(m, off, 64));
    __shared__ float smem[16];
    int lane = threadIdx.x & 63, wid = threadIdx.x >> 6;
    if (lane == 0) smem[wid] = m;
    __syncthreads();
    if (threadIdx.x == 0) {
        int nw = blockDim.x >> 6;
        for (int i = 1; i < nw; ++i) m = fmaxf(m, smem[i]);
        atomicMax(maxbits, float_to_ord(m));
    }
}

// Degrees: deg_row (bucketing over row), deg_col (norm over col)
__global__ void k_count(const int* __restrict__ row, const int* __restrict__ col,
                        int* __restrict__ deg_row, int* __restrict__ deg_col) {
    int e = blockIdx.x * blockDim.x + threadIdx.x;
    if (e < N_EDGES) {
        atomicAdd(&deg_row[row[e]], 1);
        atomicAdd(&deg_col[col[e]], 1);
    }
}

// Multi-block scan, stage 1: per-block sums of deg_row
__global__ void __launch_bounds__(SCAN_B) k_scan1(const int* __restrict__ deg_row,
                                                  int* __restrict__ bsum) {
    int i = blockIdx.x * SCAN_B + threadIdx.x;
    int v = (i < N_NODES) ? deg_row[i] : 0;
    for (int off = 32; off > 0; off >>= 1) v += __shfl_down(v, off, 64);
    __shared__ int sm[SCAN_B / 64];
    int lane = threadIdx.x & 63, wid = threadIdx.x >> 6;
    if (lane == 0) sm[wid] = v;
    __syncthreads();
    if (threadIdx.x == 0) {
        int t = 0;
        for (int w = 0; w < SCAN_B / 64; ++w) t += sm[w];
        bsum[blockIdx.x] = t;
    }
}

// Stage 2: exclusive scan of 196 block sums in one small block
__global__ void __launch_bounds__(SCAN_B) k_scan2(const int* __restrict__ bsum,
                                                  int* __restrict__ boff) {
    __shared__ int temp[SCAN_B];
    int t = threadIdx.x;
    int v = (t < N_SCAN_BLOCKS) ? bsum[t] : 0;
    temp[t] = v;
    __syncthreads();
    for (int off = 1; off < SCAN_B; off <<= 1) {
        int u = (t >= off) ? temp[t - off] : 0;
        __syncthreads();
        temp[t] += u;
        __syncthreads();
    }
    if (t < N_SCAN_BLOCKS) boff[t] = temp[t] - v;  // exclusive
}

// Stage 3: per-block LDS scan + block offset -> row_ptr/cursor; dis from deg_col
__global__ void __launch_bounds__(SCAN_B) k_scan3(const int* __restrict__ deg_row,
                                                  const int* __restrict__ deg_col,
                                                  const int* __restrict__ boff,
                                                  int* __restrict__ row_ptr,
                                                  int* __restrict__ cursor,
                                                  float* __restrict__ dis) {
    __shared__ int temp[SCAN_B];
    int t = threadIdx.x;
    int i = blockIdx.x * SCAN_B + t;
    int v = (i < N_NODES) ? deg_row[i] : 0;
    temp[t] = v;
    __syncthreads();
    for (int off = 1; off < SCAN_B; off <<= 1) {
        int u = (t >= off) ? temp[t - off] : 0;
        __syncthreads();
        temp[t] += u;
        __syncthreads();
    }
    if (i < N_NODES) {
        int o = boff[blockIdx.x] + temp[t] - v;  // exclusive prefix
        row_ptr[i] = o;
        cursor[i] = o;
        int dc = deg_col[i];
        dis[i] = (dc > 0) ? rsqrtf((float)dc) : 0.0f;
        if (i == N_NODES - 1) row_ptr[N_NODES] = o + v;  // == E
    }
}

// Bucket edges by row into CSR order; precompute per-edge norm = dis[row]*dis[col]
__global__ void k_scatter(const int* __restrict__ row, const int* __restrict__ col,
                          const float* __restrict__ dis,
                          int* __restrict__ cursor, int* __restrict__ col_sorted,
                          float* __restrict__ nrm_sorted) {
    int e = blockIdx.x * blockDim.x + threadIdx.x;
    if (e < N_EDGES) {
        int r = row[e];
        int c = col[e];
        int pos = atomicAdd(&cursor[r], 1);
        col_sorted[pos] = c;
        nrm_sorted[pos] = dis[r] * dis[c];
    }
}

// One 128-thread block per node; thread d owns feature d.
// Stage edge indices + norms in LDS so per-edge x-gathers are independent loads.
__global__ void __launch_bounds__(128) k_agg(const float* __restrict__ x,
                                             const int* __restrict__ row_ptr,
                                             const int* __restrict__ col_sorted,
                                             const float* __restrict__ nrm_sorted,
                                             const unsigned int* __restrict__ maxbits,
                                             const float* __restrict__ eps_p,
                                             const float* __restrict__ p_p,
                                             float* __restrict__ out) {
    int n = blockIdx.x;
    int d = threadIdx.x;
    __shared__ int s_idx[128];
    __shared__ float s_nrm[128];
    float pp = 2.0f / (1.0f + __expf(-p_p[0]));
    float M  = pp * ord_to_float(maxbits[0]);
    int beg = row_ptr[n], end = row_ptr[n + 1];
    float S = 0.0f, T = 0.0f;
    for (int chunk = beg; chunk < end; chunk += 128) {
        int cnt = min(128, end - chunk);
        __syncthreads();
        if (d < cnt) {
            s_idx[d] = col_sorted[chunk + d];
            s_nrm[d] = nrm_sorted[chunk + d];
        }
        __syncthreads();
        #pragma unroll 4
        for (int j = 0; j < cnt; ++j) {
            int c = s_idx[j];
            float xv = x[c * D_FEAT + d];
            float sm = __expf(fmaf(pp, xv, -M));
            float w = s_nrm[j] * sm;
            S += w;
            T = fmaf(w, xv, T);
        }
    }
    float xn = x[n * D_FEAT + d];
    out[n * D_FEAT + d] = T / (S + 1e-6f) + (1.0f + eps_p[0]) * xn;
}

extern "C" void kernel_launch(void* const* d_in, const int* in_sizes, int n_in,
                              void* d_out, int out_size, void* d_ws, size_t ws_size,
                              hipStream_t stream) {
    const float* x   = (const float*)d_in[0];
    const int*   ei  = (const int*)d_in[1];   // [2, E]: row = ei[0:E], col = ei[E:2E]
    const float* eps = (const float*)d_in[2];
    const float* p   = (const float*)d_in[3];
    float* out = (float*)d_out;

    const int* row = ei;
    const int* col = ei + N_EDGES;

    // Workspace layout (4B elements)
    char* ws = (char*)d_ws;
    int*   deg_row    = (int*)ws;                                   // N
    int*   deg_col    = (int*)(ws + 4 * N_NODES);                   // N
    unsigned int* maxbits = (unsigned int*)(ws + 4 * 2 * N_NODES);  // 1
    int*   row_ptr    = (int*)(ws + 4 * (2 * N_NODES + 1));         // N+1
    int*   cursor     = (int*)(ws + 4 * (3 * N_NODES + 2));         // N
    float* dis        = (float*)(ws + 4 * (4 * N_NODES + 2));       // N
    int*   bsum       = (int*)(ws + 4 * (5 * N_NODES + 2));         // 196
    int*   boff       = (int*)(ws + 4 * (5 * N_NODES + 2 + N_SCAN_BLOCKS));
    int*   col_sorted = (int*)(ws + 4 * (5 * N_NODES + 2 + 2 * N_SCAN_BLOCKS)); // E
    float* nrm_sorted = (float*)(ws + 4 * (5 * N_NODES + 2 + 2 * N_SCAN_BLOCKS + N_EDGES)); // E
    // total ≈ 7.4 MB

    // zero deg_row + deg_col + maxbits in one shot
    hipMemsetAsync(ws, 0, 4 * (2 * N_NODES + 1), stream);

    k_max<<<2048, 256, 0, stream>>>(x, maxbits, N_NODES * D_FEAT);
    k_count<<<(N_EDGES + 255) / 256, 256, 0, stream>>>(row, col, deg_row, deg_col);
    k_scan1<<<N_SCAN_BLOCKS, SCAN_B, 0, stream>>>(deg_row, bsum);
    k_scan2<<<1, SCAN_B, 0, stream>>>(bsum, boff);
    k_scan3<<<N_SCAN_BLOCKS, SCAN_B, 0, stream>>>(deg_row, deg_col, boff, row_ptr, cursor, dis);
    k_scatter<<<(N_EDGES + 255) / 256, 256, 0, stream>>>(row, col, dis, cursor, col_sorted, nrm_sorted);
    k_agg<<<N_NODES, D_FEAT, 0, stream>>>(x, row_ptr, col_sorted, nrm_sorted, maxbits, eps, p, out);
}